// Round 1
// baseline (910.659 us; speedup 1.0000x reference)
//
#include <hip/hip_runtime.h>
#include <hip/hip_bf16.h>
#include <math.h>

#define Hh 32
#define Nseq 8192
#define Dh 128
#define NBd 32          // number of 256-row chunks / key blocks
#define BLKSZ 256
#define SAMP 256
#define KVT 512         // block keys + sampled keys per chunk
#define CHK 64          // kv inner chunk
#define NCH 8
#define LOG32 3.4657359027997265f
#define SCALE 0.088388347648318447f

typedef float f32x4 __attribute__((ext_vector_type(4)));
typedef __bf16 bf16x8 __attribute__((ext_vector_type(8)));

__device__ __forceinline__ f32x4 mfma16(bf16x8 a, bf16x8 b, f32x4 c) {
  return __builtin_amdgcn_mfma_f32_16x16x32_bf16(a, b, c, 0, 0, 0);
}

__device__ __forceinline__ bf16x8 cvt8(const float* __restrict__ p) {
  float4 a = ((const float4*)p)[0];
  float4 b = ((const float4*)p)[1];
  bf16x8 r;
  r[0] = (__bf16)a.x; r[1] = (__bf16)a.y; r[2] = (__bf16)a.z; r[3] = (__bf16)a.w;
  r[4] = (__bf16)b.x; r[5] = (__bf16)b.y; r[6] = (__bf16)b.z; r[7] = (__bf16)b.w;
  return r;
}

__device__ __forceinline__ f32x4 vmax4(f32x4 a, f32x4 b) {
  f32x4 r;
  r[0] = fmaxf(a[0], b[0]); r[1] = fmaxf(a[1], b[1]);
  r[2] = fmaxf(a[2], b[2]); r[3] = fmaxf(a[3], b[3]);
  return r;
}

// ---------------- LSH hash: bucket id per row (q and k) ----------------
// one wave per row; fp64 accumulation so the sign matches the fp32 numpy
// reference's true sign; Gray permutation = bin ^ (bin>>1).
__global__ __launch_bounds__(256) void lsh_hash_kernel(
    const float* __restrict__ q, const float* __restrict__ k,
    const float* __restrict__ proj, int* __restrict__ buckets) {
  int wid = (blockIdx.x << 2) | (threadIdx.x >> 6);
  int l = threadIdx.x & 63;
  int tensor = wid >> 18;                  // 0 = q, 1 = k  (32*8192 = 2^18)
  int row = wid & (Hh * Nseq - 1);
  const float* x = (tensor ? k : q) + (size_t)row * Dh + 2 * l;
  float2 xv = *(const float2*)x;
  double a0 = (double)xv.x, a1 = (double)xv.y;
  double acc[7];
#pragma unroll
  for (int j = 0; j < 7; j++)
    acc[j] = a0 * (double)proj[(2 * l) * 7 + j] + a1 * (double)proj[(2 * l + 1) * 7 + j];
#pragma unroll
  for (int j = 0; j < 7; j++) {
#pragma unroll
    for (int s = 1; s < 64; s <<= 1) acc[j] += __shfl_xor(acc[j], s);
  }
  if (l == 0) {
    int bin = 0;
#pragma unroll
    for (int j = 0; j < 7; j++) bin |= (acc[j] > 0.0 ? 1 : 0) << j;
    buckets[wid] = bin ^ (bin >> 1);
  }
}

// ---------------- stable counting sort by bucket, per (tensor, head) ----------------
__global__ __launch_bounds__(64) void bucket_sort_kernel(
    const int* __restrict__ buckets, int* __restrict__ idx) {
  __shared__ unsigned hist[64][128];
  int t = threadIdx.x;
  int base = blockIdx.x * Nseq;
  for (int b = 0; b < 128; b++) hist[t][b] = 0;
  __syncthreads();
  for (int i = 0; i < 128; i++) {
    int b = buckets[base + t * 128 + i];
    hist[t][b]++;
  }
  __syncthreads();
  int b0 = 2 * t, b1 = 2 * t + 1;
  unsigned tot0 = 0, tot1 = 0;
  for (int tt = 0; tt < 64; tt++) { unsigned h = hist[tt][b0]; hist[tt][b0] = tot0; tot0 += h; }
  for (int tt = 0; tt < 64; tt++) { unsigned h = hist[tt][b1]; hist[tt][b1] = tot1; tot1 += h; }
  unsigned pair = tot0 + tot1;
  unsigned scan = pair;
  for (int s = 1; s < 64; s <<= 1) {
    unsigned u = __shfl_up(scan, s);
    if (t >= s) scan += u;
  }
  unsigned start0 = scan - pair;      // exclusive prefix over bucket totals
  unsigned start1 = start0 + tot0;
  __syncthreads();
  for (int tt = 0; tt < 64; tt++) { hist[tt][b0] += start0; hist[tt][b1] += start1; }
  __syncthreads();
  for (int i = 0; i < 128; i++) {
    int gi = t * 128 + i;
    int b = buckets[base + gi];
    unsigned pos = hist[t][b]++;
    idx[base + pos] = gi;            // stable: threads cover contiguous in-order chunks
  }
}

// ---------------- fused block-diagonal + residual attention ----------------
// one workgroup per (head, 256-query chunk); single online softmax over the
// union of 256 block keys (score s) and 256 sampled keys (score s+log32,
// same-block samples masked) -> final combined output directly.
__global__ __launch_bounds__(512) void hyper_attn_kernel(
    const float* __restrict__ q, const float* __restrict__ k, const float* __restrict__ v,
    const int* __restrict__ sampled, const int* __restrict__ q_idx,
    const int* __restrict__ k_idx, float* __restrict__ out) {
  __shared__ int s_orig[KVT];
  __shared__ float s_add[KVT];
  __shared__ __attribute__((aligned(16))) __bf16 s_vt[Dh][72];      // V^T chunk, padded stride
  __shared__ __attribute__((aligned(16))) __bf16 s_p[8][32][72];    // per-wave P staging

  const int c = blockIdx.x, bh = blockIdx.y;
  const int tid = threadIdx.x;
  const int w = tid >> 6, l = tid & 63;
  const int l4 = l >> 4, lm = l & 15;

  // kv list: originals rows (via sorted key index) + score addend per column
  {
    int jj = tid;
    if (jj < BLKSZ) {
      s_orig[jj] = k_idx[bh * Nseq + c * BLKSZ + jj];
      s_add[jj] = 0.0f;
    } else {
      int sp = sampled[bh * SAMP + (jj - BLKSZ)];
      s_orig[jj] = k_idx[bh * Nseq + sp];
      s_add[jj] = ((sp >> 8) == c) ? -1e38f : LOG32;
    }
  }

  // Q fragments in registers: A-frag row = lane&15, k = (lane>>4)*8..+8
  bf16x8 qf[2][4];
  const int* qi = q_idx + bh * Nseq + c * BLKSZ + w * 32;
#pragma unroll
  for (int rt = 0; rt < 2; rt++) {
    int orig = qi[rt * 16 + lm];
    const float* qp = q + ((size_t)bh * Nseq + orig) * Dh + l4 * 8;
#pragma unroll
    for (int dc = 0; dc < 4; dc++) qf[rt][dc] = cvt8(qp + dc * 32);
  }

  f32x4 O[2][8];
  f32x4 mrow[2], lrow[2];
#pragma unroll
  for (int rt = 0; rt < 2; rt++) {
    mrow[rt][0] = -INFINITY; mrow[rt][1] = -INFINITY; mrow[rt][2] = -INFINITY; mrow[rt][3] = -INFINITY;
    lrow[rt][0] = 0.f; lrow[rt][1] = 0.f; lrow[rt][2] = 0.f; lrow[rt][3] = 0.f;
#pragma unroll
    for (int dt = 0; dt < 8; dt++) { O[rt][dt][0]=0.f; O[rt][dt][1]=0.f; O[rt][dt][2]=0.f; O[rt][dt][3]=0.f; }
  }

  __syncthreads();

  for (int ch = 0; ch < NCH; ch++) {
    // stage V^T for this 64-key chunk: s_vt[d][j_local]
    {
      int jj = tid >> 3;
      int d0 = (tid & 7) * 16;
      int orig = s_orig[ch * CHK + jj];
      const float4* vp = (const float4*)(v + ((size_t)bh * Nseq + orig) * Dh + d0);
      float4 A = vp[0], B = vp[1], C = vp[2], Dv = vp[3];
      float tmp[16] = {A.x,A.y,A.z,A.w,B.x,B.y,B.z,B.w,C.x,C.y,C.z,C.w,Dv.x,Dv.y,Dv.z,Dv.w};
#pragma unroll
      for (int dd = 0; dd < 16; dd++) s_vt[d0 + dd][jj] = (__bf16)tmp[dd];
    }
    __syncthreads();

    // S = Q K^T (+scale +addend) for the 64 keys
    f32x4 sc[2][4];
#pragma unroll
    for (int ct = 0; ct < 4; ct++) {
      int col = ch * CHK + ct * 16 + lm;
      int korig = s_orig[col];
      float add = s_add[col];
      const float* kp = k + ((size_t)bh * Nseq + korig) * Dh + l4 * 8;
      f32x4 acc0, acc1;
      acc0[0]=0.f;acc0[1]=0.f;acc0[2]=0.f;acc0[3]=0.f;
      acc1[0]=0.f;acc1[1]=0.f;acc1[2]=0.f;acc1[3]=0.f;
#pragma unroll
      for (int dc = 0; dc < 4; dc++) {
        bf16x8 kf = cvt8(kp + dc * 32);
        acc0 = mfma16(qf[0][dc], kf, acc0);
        acc1 = mfma16(qf[1][dc], kf, acc1);
      }
#pragma unroll
      for (int r = 0; r < 4; r++) {
        sc[0][ct][r] = acc0[r] * SCALE + add;
        sc[1][ct][r] = acc1[r] * SCALE + add;
      }
    }

    // online softmax update (rows = C-layout rows (l>>4)*4+r, cols across 16 lanes)
#pragma unroll
    for (int rt = 0; rt < 2; rt++) {
      f32x4 mc = vmax4(vmax4(sc[rt][0], sc[rt][1]), vmax4(sc[rt][2], sc[rt][3]));
#pragma unroll
      for (int s = 1; s < 16; s <<= 1) {
        f32x4 o;
        o[0] = __shfl_xor(mc[0], s); o[1] = __shfl_xor(mc[1], s);
        o[2] = __shfl_xor(mc[2], s); o[3] = __shfl_xor(mc[3], s);
        mc = vmax4(mc, o);
      }
      f32x4 mn = vmax4(mrow[rt], mc);
      f32x4 alpha;
#pragma unroll
      for (int r = 0; r < 4; r++) alpha[r] = __expf(mrow[rt][r] - mn[r]);
      mrow[rt] = mn;
#pragma unroll
      for (int dt = 0; dt < 8; dt++) O[rt][dt] *= alpha;
      f32x4 rs;
      rs[0]=0.f; rs[1]=0.f; rs[2]=0.f; rs[3]=0.f;
#pragma unroll
      for (int ct = 0; ct < 4; ct++) {
#pragma unroll
        for (int r = 0; r < 4; r++) {
          float pf = __expf(sc[rt][ct][r] - mn[r]);
          __bf16 pb = (__bf16)pf;
          s_p[w][rt * 16 + l4 * 4 + r][ct * 16 + lm] = pb;
          rs[r] += (float)pb;          // sum the rounded value PV will use
        }
      }
#pragma unroll
      for (int s = 1; s < 16; s <<= 1) {
        f32x4 o;
        o[0] = __shfl_xor(rs[0], s); o[1] = __shfl_xor(rs[1], s);
        o[2] = __shfl_xor(rs[2], s); o[3] = __shfl_xor(rs[3], s);
        rs += o;
      }
      lrow[rt] = lrow[rt] * alpha + rs;
    }

    // PV: A = P (rows=q, k=key local), B = V^T (col=d, k=key local)
#pragma unroll
    for (int kc = 0; kc < 2; kc++) {
      bf16x8 pa0 = *(const bf16x8*)&s_p[w][lm][kc * 32 + l4 * 8];
      bf16x8 pa1 = *(const bf16x8*)&s_p[w][16 + lm][kc * 32 + l4 * 8];
#pragma unroll
      for (int dt = 0; dt < 8; dt++) {
        bf16x8 vb = *(const bf16x8*)&s_vt[dt * 16 + lm][kc * 32 + l4 * 8];
        O[0][dt] = mfma16(pa0, vb, O[0][dt]);
        O[1][dt] = mfma16(pa1, vb, O[1][dt]);
      }
    }
    __syncthreads();
  }

  // epilogue: normalize and scatter to original row order
#pragma unroll
  for (int rt = 0; rt < 2; rt++) {
    f32x4 inv;
#pragma unroll
    for (int r = 0; r < 4; r++) inv[r] = 1.0f / lrow[rt][r];
    int orow[4];
#pragma unroll
    for (int r = 0; r < 4; r++)
      orow[r] = q_idx[bh * Nseq + c * BLKSZ + w * 32 + rt * 16 + l4 * 4 + r];
#pragma unroll
    for (int r = 0; r < 4; r++) {
      float* op = out + ((size_t)bh * Nseq + orow[r]) * Dh + lm;
#pragma unroll
      for (int dt = 0; dt < 8; dt++) op[dt * 16] = O[rt][dt][r] * inv[r];
    }
  }
}

extern "C" void kernel_launch(void* const* d_in, const int* in_sizes, int n_in,
                              void* d_out, int out_size, void* d_ws, size_t ws_size,
                              hipStream_t stream) {
  const float* q    = (const float*)d_in[0];
  const float* k    = (const float*)d_in[1];
  const float* v    = (const float*)d_in[2];
  const float* proj = (const float*)d_in[3];
  const int* samp   = (const int*)d_in[4];
  float* out = (float*)d_out;

  int* buckets = (int*)d_ws;                   // [2][32][8192]
  int* idx = buckets + 2 * Hh * Nseq;          // [2][32][8192]: q_idx, k_idx

  lsh_hash_kernel<<<(2 * Hh * Nseq) / 4, 256, 0, stream>>>(q, k, proj, buckets);
  bucket_sort_kernel<<<2 * Hh, 64, 0, stream>>>(buckets, idx);
  hyper_attn_kernel<<<dim3(NBd, Hh), 512, 0, stream>>>(
      q, k, v, samp, idx /*q_idx*/, idx + Hh * Nseq /*k_idx*/, out);
}

// Round 3
// 561.308 us; speedup vs baseline: 1.6224x; 1.6224x over previous
//
#include <hip/hip_runtime.h>
#include <hip/hip_bf16.h>
#include <math.h>

#define Hh 32
#define Nseq 8192
#define Dh 128
#define NBd 32          // number of 256-row chunks / key blocks
#define BLKSZ 256
#define SAMP 256
#define KVT 512         // block keys + sampled keys per chunk
#define CHK 64          // kv inner chunk
#define NCH 8
#define LOG32 3.4657359027997265f
#define SCALE 0.088388347648318447f

typedef float f32x4 __attribute__((ext_vector_type(4)));
typedef __bf16 bf16x8 __attribute__((ext_vector_type(8)));

__device__ __forceinline__ f32x4 mfma16(bf16x8 a, bf16x8 b, f32x4 c) {
  return __builtin_amdgcn_mfma_f32_16x16x32_bf16(a, b, c, 0, 0, 0);
}

__device__ __forceinline__ bf16x8 cvt8(const float* __restrict__ p) {
  float4 a = ((const float4*)p)[0];
  float4 b = ((const float4*)p)[1];
  bf16x8 r;
  r[0] = (__bf16)a.x; r[1] = (__bf16)a.y; r[2] = (__bf16)a.z; r[3] = (__bf16)a.w;
  r[4] = (__bf16)b.x; r[5] = (__bf16)b.y; r[6] = (__bf16)b.z; r[7] = (__bf16)b.w;
  return r;
}

__device__ __forceinline__ f32x4 vmax4(f32x4 a, f32x4 b) {
  f32x4 r;
  r[0] = fmaxf(a[0], b[0]); r[1] = fmaxf(a[1], b[1]);
  r[2] = fmaxf(a[2], b[2]); r[3] = fmaxf(a[3], b[3]);
  return r;
}

// ---------------- LSH hash: one thread per row, sequential fp64 ----------------
// proj addresses are wave-uniform -> scalar loads (3.5 KB, L1-resident).
// fp64 accumulation keeps the sign decision exact vs the fp32 reference.
__global__ __launch_bounds__(256) void lsh_hash_kernel(
    const float* __restrict__ q, const float* __restrict__ k,
    const float* __restrict__ proj, int* __restrict__ buckets) {
  int row = blockIdx.x * 256 + threadIdx.x;          // 0 .. 2*32*8192-1
  const float* x = ((row >> 18) ? k : q) + (size_t)(row & (Hh * Nseq - 1)) * Dh;
  double acc[7] = {0, 0, 0, 0, 0, 0, 0};
#pragma unroll 2
  for (int d0 = 0; d0 < Dh; d0 += 4) {
    float4 xv = *(const float4*)(x + d0);
    double x0 = (double)xv.x, x1 = (double)xv.y, x2 = (double)xv.z, x3 = (double)xv.w;
#pragma unroll
    for (int j = 0; j < 7; j++) {
      acc[j] = fma(x0, (double)proj[(d0 + 0) * 7 + j], acc[j]);
      acc[j] = fma(x1, (double)proj[(d0 + 1) * 7 + j], acc[j]);
      acc[j] = fma(x2, (double)proj[(d0 + 2) * 7 + j], acc[j]);
      acc[j] = fma(x3, (double)proj[(d0 + 3) * 7 + j], acc[j]);
    }
  }
  int bin = 0;
#pragma unroll
  for (int j = 0; j < 7; j++) bin |= (acc[j] > 0.0 ? 1 : 0) << j;
  buckets[row] = bin ^ (bin >> 1);
}

// ---------------- stable counting sort by bucket, per (tensor, head) ----------------
// (R1 version, known good)
__global__ __launch_bounds__(64) void bucket_sort_kernel(
    const int* __restrict__ buckets, int* __restrict__ idx) {
  __shared__ unsigned hist[64][128];
  int t = threadIdx.x;
  int base = blockIdx.x * Nseq;
  for (int b = 0; b < 128; b++) hist[t][b] = 0;
  __syncthreads();
  for (int i = 0; i < 128; i++) {
    int b = buckets[base + t * 128 + i];
    hist[t][b]++;
  }
  __syncthreads();
  int b0 = 2 * t, b1 = 2 * t + 1;
  unsigned tot0 = 0, tot1 = 0;
  for (int tt = 0; tt < 64; tt++) { unsigned h = hist[tt][b0]; hist[tt][b0] = tot0; tot0 += h; }
  for (int tt = 0; tt < 64; tt++) { unsigned h = hist[tt][b1]; hist[tt][b1] = tot1; tot1 += h; }
  unsigned pair = tot0 + tot1;
  unsigned scan = pair;
  for (int s = 1; s < 64; s <<= 1) {
    unsigned u = __shfl_up(scan, s);
    if (t >= s) scan += u;
  }
  unsigned start0 = scan - pair;      // exclusive prefix over bucket totals
  unsigned start1 = start0 + tot0;
  __syncthreads();
  for (int tt = 0; tt < 64; tt++) { hist[tt][b0] += start0; hist[tt][b1] += start1; }
  __syncthreads();
  for (int i = 0; i < 128; i++) {
    int gi = t * 128 + i;
    int b = buckets[base + gi];
    unsigned pos = hist[t][b]++;
    idx[base + pos] = gi;            // stable: threads cover contiguous in-order chunks
  }
}

// ---------------- fused block-diagonal + residual attention ----------------
// (R1 version, known good)
__global__ __launch_bounds__(512) void hyper_attn_kernel(
    const float* __restrict__ q, const float* __restrict__ k, const float* __restrict__ v,
    const int* __restrict__ sampled, const int* __restrict__ q_idx,
    const int* __restrict__ k_idx, float* __restrict__ out) {
  __shared__ int s_orig[KVT];
  __shared__ float s_add[KVT];
  __shared__ __attribute__((aligned(16))) __bf16 s_vt[Dh][72];      // V^T chunk, padded stride
  __shared__ __attribute__((aligned(16))) __bf16 s_p[8][32][72];    // per-wave P staging

  const int c = blockIdx.x, bh = blockIdx.y;
  const int tid = threadIdx.x;
  const int w = tid >> 6, l = tid & 63;
  const int l4 = l >> 4, lm = l & 15;

  // kv list: originals rows (via sorted key index) + score addend per column
  {
    int jj = tid;
    if (jj < BLKSZ) {
      s_orig[jj] = k_idx[bh * Nseq + c * BLKSZ + jj];
      s_add[jj] = 0.0f;
    } else {
      int sp = sampled[bh * SAMP + (jj - BLKSZ)];
      s_orig[jj] = k_idx[bh * Nseq + sp];
      s_add[jj] = ((sp >> 8) == c) ? -1e38f : LOG32;
    }
  }

  // Q fragments in registers: A-frag row = lane&15, k = (lane>>4)*8..+8
  bf16x8 qf[2][4];
  const int* qi = q_idx + bh * Nseq + c * BLKSZ + w * 32;
#pragma unroll
  for (int rt = 0; rt < 2; rt++) {
    int orig = qi[rt * 16 + lm];
    const float* qp = q + ((size_t)bh * Nseq + orig) * Dh + l4 * 8;
#pragma unroll
    for (int dc = 0; dc < 4; dc++) qf[rt][dc] = cvt8(qp + dc * 32);
  }

  f32x4 O[2][8];
  f32x4 mrow[2], lrow[2];
#pragma unroll
  for (int rt = 0; rt < 2; rt++) {
    mrow[rt][0] = -INFINITY; mrow[rt][1] = -INFINITY; mrow[rt][2] = -INFINITY; mrow[rt][3] = -INFINITY;
    lrow[rt][0] = 0.f; lrow[rt][1] = 0.f; lrow[rt][2] = 0.f; lrow[rt][3] = 0.f;
#pragma unroll
    for (int dt = 0; dt < 8; dt++) { O[rt][dt][0]=0.f; O[rt][dt][1]=0.f; O[rt][dt][2]=0.f; O[rt][dt][3]=0.f; }
  }

  __syncthreads();

  for (int ch = 0; ch < NCH; ch++) {
    // stage V^T for this 64-key chunk: s_vt[d][j_local]
    {
      int jj = tid >> 3;
      int d0 = (tid & 7) * 16;
      int orig = s_orig[ch * CHK + jj];
      const float4* vp = (const float4*)(v + ((size_t)bh * Nseq + orig) * Dh + d0);
      float4 A = vp[0], B = vp[1], C = vp[2], Dv = vp[3];
      float tmp[16] = {A.x,A.y,A.z,A.w,B.x,B.y,B.z,B.w,C.x,C.y,C.z,C.w,Dv.x,Dv.y,Dv.z,Dv.w};
#pragma unroll
      for (int dd = 0; dd < 16; dd++) s_vt[d0 + dd][jj] = (__bf16)tmp[dd];
    }
    __syncthreads();

    // S = Q K^T (+scale +addend) for the 64 keys
    f32x4 sc[2][4];
#pragma unroll
    for (int ct = 0; ct < 4; ct++) {
      int col = ch * CHK + ct * 16 + lm;
      int korig = s_orig[col];
      float add = s_add[col];
      const float* kp = k + ((size_t)bh * Nseq + korig) * Dh + l4 * 8;
      f32x4 acc0, acc1;
      acc0[0]=0.f;acc0[1]=0.f;acc0[2]=0.f;acc0[3]=0.f;
      acc1[0]=0.f;acc1[1]=0.f;acc1[2]=0.f;acc1[3]=0.f;
#pragma unroll
      for (int dc = 0; dc < 4; dc++) {
        bf16x8 kf = cvt8(kp + dc * 32);
        acc0 = mfma16(qf[0][dc], kf, acc0);
        acc1 = mfma16(qf[1][dc], kf, acc1);
      }
#pragma unroll
      for (int r = 0; r < 4; r++) {
        sc[0][ct][r] = acc0[r] * SCALE + add;
        sc[1][ct][r] = acc1[r] * SCALE + add;
      }
    }

    // online softmax update (rows = C-layout rows (l>>4)*4+r, cols across 16 lanes)
#pragma unroll
    for (int rt = 0; rt < 2; rt++) {
      f32x4 mc = vmax4(vmax4(sc[rt][0], sc[rt][1]), vmax4(sc[rt][2], sc[rt][3]));
#pragma unroll
      for (int s = 1; s < 16; s <<= 1) {
        f32x4 o;
        o[0] = __shfl_xor(mc[0], s); o[1] = __shfl_xor(mc[1], s);
        o[2] = __shfl_xor(mc[2], s); o[3] = __shfl_xor(mc[3], s);
        mc = vmax4(mc, o);
      }
      f32x4 mn = vmax4(mrow[rt], mc);
      f32x4 alpha;
#pragma unroll
      for (int r = 0; r < 4; r++) alpha[r] = __expf(mrow[rt][r] - mn[r]);
      mrow[rt] = mn;
#pragma unroll
      for (int dt = 0; dt < 8; dt++) O[rt][dt] *= alpha;
      f32x4 rs;
      rs[0]=0.f; rs[1]=0.f; rs[2]=0.f; rs[3]=0.f;
#pragma unroll
      for (int ct = 0; ct < 4; ct++) {
#pragma unroll
        for (int r = 0; r < 4; r++) {
          float pf = __expf(sc[rt][ct][r] - mn[r]);
          __bf16 pb = (__bf16)pf;
          s_p[w][rt * 16 + l4 * 4 + r][ct * 16 + lm] = pb;
          rs[r] += (float)pb;          // sum the rounded value PV will use
        }
      }
#pragma unroll
      for (int s = 1; s < 16; s <<= 1) {
        f32x4 o;
        o[0] = __shfl_xor(rs[0], s); o[1] = __shfl_xor(rs[1], s);
        o[2] = __shfl_xor(rs[2], s); o[3] = __shfl_xor(rs[3], s);
        rs += o;
      }
      lrow[rt] = lrow[rt] * alpha + rs;
    }

    // PV: A = P (rows=q, k=key local), B = V^T (col=d, k=key local)
#pragma unroll
    for (int kc = 0; kc < 2; kc++) {
      bf16x8 pa0 = *(const bf16x8*)&s_p[w][lm][kc * 32 + l4 * 8];
      bf16x8 pa1 = *(const bf16x8*)&s_p[w][16 + lm][kc * 32 + l4 * 8];
#pragma unroll
      for (int dt = 0; dt < 8; dt++) {
        bf16x8 vb = *(const bf16x8*)&s_vt[dt * 16 + lm][kc * 32 + l4 * 8];
        O[0][dt] = mfma16(pa0, vb, O[0][dt]);
        O[1][dt] = mfma16(pa1, vb, O[1][dt]);
      }
    }
    __syncthreads();
  }

  // epilogue: normalize and scatter to original row order
#pragma unroll
  for (int rt = 0; rt < 2; rt++) {
    f32x4 inv;
#pragma unroll
    for (int r = 0; r < 4; r++) inv[r] = 1.0f / lrow[rt][r];
    int orow[4];
#pragma unroll
    for (int r = 0; r < 4; r++)
      orow[r] = q_idx[bh * Nseq + c * BLKSZ + w * 32 + rt * 16 + l4 * 4 + r];
#pragma unroll
    for (int r = 0; r < 4; r++) {
      float* op = out + ((size_t)bh * Nseq + orow[r]) * Dh + lm;
#pragma unroll
      for (int dt = 0; dt < 8; dt++) op[dt * 16] = O[rt][dt][r] * inv[r];
    }
  }
}

extern "C" void kernel_launch(void* const* d_in, const int* in_sizes, int n_in,
                              void* d_out, int out_size, void* d_ws, size_t ws_size,
                              hipStream_t stream) {
  const float* q    = (const float*)d_in[0];
  const float* k    = (const float*)d_in[1];
  const float* v    = (const float*)d_in[2];
  const float* proj = (const float*)d_in[3];
  const int* samp   = (const int*)d_in[4];
  float* out = (float*)d_out;

  int* buckets = (int*)d_ws;                   // [2][32][8192]
  int* idx = buckets + 2 * Hh * Nseq;          // [2][32][8192]: q_idx, k_idx

  lsh_hash_kernel<<<(2 * Hh * Nseq) / 256, 256, 0, stream>>>(q, k, proj, buckets);
  bucket_sort_kernel<<<2 * Hh, 64, 0, stream>>>(buckets, idx);
  hyper_attn_kernel<<<dim3(NBd, Hh), 512, 0, stream>>>(
      q, k, v, samp, idx /*q_idx*/, idx + Hh * Nseq /*k_idx*/, out);
}

// Round 5
// 374.152 us; speedup vs baseline: 2.4339x; 1.5002x over previous
//
#include <hip/hip_runtime.h>
#include <hip/hip_bf16.h>
#include <math.h>

#define Hh 32
#define Nseq 8192
#define Dh 128
#define NBd 32          // number of 256-row chunks / key blocks
#define BLKSZ 256
#define SAMP 256
#define KVT 512         // block keys + sampled keys per chunk
#define CHK 64          // kv inner chunk
#define NCH 8
#define LOG32 3.4657359027997265f
#define SCALE 0.088388347648318447f
#define SKW 136         // s_k row width: 128 d + 8 pad (272B rows, 16B-aligned)

typedef float f32x4 __attribute__((ext_vector_type(4)));
typedef __bf16 bf16x8 __attribute__((ext_vector_type(8)));

__device__ __forceinline__ f32x4 mfma16(bf16x8 a, bf16x8 b, f32x4 c) {
  return __builtin_amdgcn_mfma_f32_16x16x32_bf16(a, b, c, 0, 0, 0);
}

__device__ __forceinline__ bf16x8 cvt8(const float* __restrict__ p) {
  float4 a = ((const float4*)p)[0];
  float4 b = ((const float4*)p)[1];
  bf16x8 r;
  r[0] = (__bf16)a.x; r[1] = (__bf16)a.y; r[2] = (__bf16)a.z; r[3] = (__bf16)a.w;
  r[4] = (__bf16)b.x; r[5] = (__bf16)b.y; r[6] = (__bf16)b.z; r[7] = (__bf16)b.w;
  return r;
}

__device__ __forceinline__ f32x4 vmax4(f32x4 a, f32x4 b) {
  f32x4 r;
  r[0] = fmaxf(a[0], b[0]); r[1] = fmaxf(a[1], b[1]);
  r[2] = fmaxf(a[2], b[2]); r[3] = fmaxf(a[3], b[3]);
  return r;
}

// ---------------- LSH hash: one thread per row, sequential fp64 ----------------
__global__ __launch_bounds__(256) void lsh_hash_kernel(
    const float* __restrict__ q, const float* __restrict__ k,
    const float* __restrict__ proj, int* __restrict__ buckets) {
  int row = blockIdx.x * 256 + threadIdx.x;          // 0 .. 2*32*8192-1
  const float* x = ((row >> 18) ? k : q) + (size_t)(row & (Hh * Nseq - 1)) * Dh;
  double acc[7] = {0, 0, 0, 0, 0, 0, 0};
#pragma unroll 2
  for (int d0 = 0; d0 < Dh; d0 += 4) {
    float4 xv = *(const float4*)(x + d0);
    double x0 = (double)xv.x, x1 = (double)xv.y, x2 = (double)xv.z, x3 = (double)xv.w;
#pragma unroll
    for (int j = 0; j < 7; j++) {
      acc[j] = fma(x0, (double)proj[(d0 + 0) * 7 + j], acc[j]);
      acc[j] = fma(x1, (double)proj[(d0 + 1) * 7 + j], acc[j]);
      acc[j] = fma(x2, (double)proj[(d0 + 2) * 7 + j], acc[j]);
      acc[j] = fma(x3, (double)proj[(d0 + 3) * 7 + j], acc[j]);
    }
  }
  int bin = 0;
#pragma unroll
  for (int j = 0; j < 7; j++) bin |= (acc[j] > 0.0 ? 1 : 0) << j;
  buckets[row] = bin ^ (bin >> 1);
}

// ---------------- stable counting sort by bucket, per (tensor, head) ----------------
// (known good)
__global__ __launch_bounds__(64) void bucket_sort_kernel(
    const int* __restrict__ buckets, int* __restrict__ idx) {
  __shared__ unsigned hist[64][128];
  int t = threadIdx.x;
  int base = blockIdx.x * Nseq;
  for (int b = 0; b < 128; b++) hist[t][b] = 0;
  __syncthreads();
  for (int i = 0; i < 128; i++) {
    int b = buckets[base + t * 128 + i];
    hist[t][b]++;
  }
  __syncthreads();
  int b0 = 2 * t, b1 = 2 * t + 1;
  unsigned tot0 = 0, tot1 = 0;
  for (int tt = 0; tt < 64; tt++) { unsigned h = hist[tt][b0]; hist[tt][b0] = tot0; tot0 += h; }
  for (int tt = 0; tt < 64; tt++) { unsigned h = hist[tt][b1]; hist[tt][b1] = tot1; tot1 += h; }
  unsigned pair = tot0 + tot1;
  unsigned scan = pair;
  for (int s = 1; s < 64; s <<= 1) {
    unsigned u = __shfl_up(scan, s);
    if (t >= s) scan += u;
  }
  unsigned start0 = scan - pair;      // exclusive prefix over bucket totals
  unsigned start1 = start0 + tot0;
  __syncthreads();
  for (int tt = 0; tt < 64; tt++) { hist[tt][b0] += start0; hist[tt][b1] += start1; }
  __syncthreads();
  for (int i = 0; i < 128; i++) {
    int gi = t * 128 + i;
    int b = buckets[base + gi];
    unsigned pos = hist[t][b]++;
    idx[base + pos] = gi;            // stable: threads cover contiguous in-order chunks
  }
}

// ---------------- fused block-diagonal + residual attention ----------------
__global__ __launch_bounds__(512) void hyper_attn_kernel(
    const float* __restrict__ q, const float* __restrict__ k, const float* __restrict__ v,
    const int* __restrict__ sampled, const int* __restrict__ q_idx,
    const int* __restrict__ k_idx, float* __restrict__ out) {
  __shared__ int s_orig[KVT];
  __shared__ float s_add[KVT];
  __shared__ __attribute__((aligned(16))) __bf16 s_k[CHK][SKW];     // K chunk: row=key, 128 d
  __shared__ __attribute__((aligned(16))) __bf16 s_vt[Dh][72];      // V^T chunk, row=d
  __shared__ __attribute__((aligned(16))) __bf16 s_p[8][32][72];    // per-wave P staging

  const int c = blockIdx.x, bh = blockIdx.y;
  const int tid = threadIdx.x;
  const int w = tid >> 6, l = tid & 63;
  const int l4 = l >> 4, lm = l & 15;

  // kv list: original rows (via sorted key index) + score addend per column
  {
    int jj = tid;
    if (jj < BLKSZ) {
      s_orig[jj] = k_idx[bh * Nseq + c * BLKSZ + jj];
      s_add[jj] = 0.0f;
    } else {
      int sp = sampled[bh * SAMP + (jj - BLKSZ)];
      s_orig[jj] = k_idx[bh * Nseq + sp];
      s_add[jj] = ((sp >> 8) == c) ? -1e38f : LOG32;
    }
  }

  // Q fragments in registers: A-frag row = lane&15, k = (lane>>4)*8..+8
  bf16x8 qf[2][4];
  const int* qi = q_idx + bh * Nseq + c * BLKSZ + w * 32;
#pragma unroll
  for (int rt = 0; rt < 2; rt++) {
    int orig = qi[rt * 16 + lm];
    const float* qp = q + ((size_t)bh * Nseq + orig) * Dh + l4 * 8;
#pragma unroll
    for (int dc = 0; dc < 4; dc++) qf[rt][dc] = cvt8(qp + dc * 32);
  }

  f32x4 O[2][8];
  f32x4 mrow[2], lrow[2];
#pragma unroll
  for (int rt = 0; rt < 2; rt++) {
    mrow[rt][0] = -INFINITY; mrow[rt][1] = -INFINITY; mrow[rt][2] = -INFINITY; mrow[rt][3] = -INFINITY;
    lrow[rt][0] = 0.f; lrow[rt][1] = 0.f; lrow[rt][2] = 0.f; lrow[rt][3] = 0.f;
#pragma unroll
    for (int dt = 0; dt < 8; dt++) { O[rt][dt][0]=0.f; O[rt][dt][1]=0.f; O[rt][dt][2]=0.f; O[rt][dt][3]=0.f; }
  }

  __syncthreads();

  for (int ch = 0; ch < NCH; ch++) {
    // stage K (row=key, 128 d): thread t -> key t>>3, d-seg (t&7)*16; b128
    // writes, banks (4r+8p) mod 32 cover all 32 uniformly.
    {
      int jk = tid >> 3, pk = tid & 7;
      int origk = s_orig[ch * CHK + jk];
      const float* kp = k + ((size_t)bh * Nseq + origk) * Dh + pk * 16;
      *(bf16x8*)&s_k[jk][pk * 16]     = cvt8(kp);
      *(bf16x8*)&s_k[jk][pk * 16 + 8] = cvt8(kp + 8);
    }
    // stage V^T (row=d): wave w -> d-block w*16 (uniform row per wave),
    // lane l -> key l; 64 lanes' b16 writes span all 32 banks -> conflict-free.
    {
      int origv = s_orig[ch * CHK + l];
      const float* vp = v + ((size_t)bh * Nseq + origv) * Dh + w * 16;
      float4 A = ((const float4*)vp)[0], B = ((const float4*)vp)[1];
      float4 C = ((const float4*)vp)[2], Dv = ((const float4*)vp)[3];
      float tmp[16] = {A.x,A.y,A.z,A.w,B.x,B.y,B.z,B.w,C.x,C.y,C.z,C.w,Dv.x,Dv.y,Dv.z,Dv.w};
#pragma unroll
      for (int dd = 0; dd < 16; dd++) s_vt[w * 16 + dd][l] = (__bf16)tmp[dd];
    }
    __syncthreads();

    // S = Q K^T (+scale +addend) for the 64 keys, all from LDS
    f32x4 sc[2][4];
#pragma unroll
    for (int ct = 0; ct < 4; ct++) {
      f32x4 acc0, acc1;
      acc0[0]=0.f;acc0[1]=0.f;acc0[2]=0.f;acc0[3]=0.f;
      acc1[0]=0.f;acc1[1]=0.f;acc1[2]=0.f;acc1[3]=0.f;
#pragma unroll
      for (int dc = 0; dc < 4; dc++) {
        bf16x8 kf = *(const bf16x8*)&s_k[ct * 16 + lm][dc * 32 + l4 * 8];
        acc0 = mfma16(qf[0][dc], kf, acc0);
        acc1 = mfma16(qf[1][dc], kf, acc1);
      }
      float add = s_add[ch * CHK + ct * 16 + lm];
#pragma unroll
      for (int r = 0; r < 4; r++) {
        sc[0][ct][r] = acc0[r] * SCALE + add;
        sc[1][ct][r] = acc1[r] * SCALE + add;
      }
    }

    // online softmax update (rows = C-layout rows (l>>4)*4+r, cols across 16 lanes)
#pragma unroll
    for (int rt = 0; rt < 2; rt++) {
      f32x4 mc = vmax4(vmax4(sc[rt][0], sc[rt][1]), vmax4(sc[rt][2], sc[rt][3]));
#pragma unroll
      for (int s = 1; s < 16; s <<= 1) {
        f32x4 o;
        o[0] = __shfl_xor(mc[0], s); o[1] = __shfl_xor(mc[1], s);
        o[2] = __shfl_xor(mc[2], s); o[3] = __shfl_xor(mc[3], s);
        mc = vmax4(mc, o);
      }
      f32x4 mn = vmax4(mrow[rt], mc);
      f32x4 alpha;
#pragma unroll
      for (int r = 0; r < 4; r++) alpha[r] = __expf(mrow[rt][r] - mn[r]);
      mrow[rt] = mn;
#pragma unroll
      for (int dt = 0; dt < 8; dt++) O[rt][dt] *= alpha;
      f32x4 rs;
      rs[0]=0.f; rs[1]=0.f; rs[2]=0.f; rs[3]=0.f;
#pragma unroll
      for (int ct = 0; ct < 4; ct++) {
#pragma unroll
        for (int r = 0; r < 4; r++) {
          float pf = __expf(sc[rt][ct][r] - mn[r]);
          __bf16 pb = (__bf16)pf;
          s_p[w][rt * 16 + l4 * 4 + r][ct * 16 + lm] = pb;
          rs[r] += (float)pb;          // sum the rounded value PV will use
        }
      }
#pragma unroll
      for (int s = 1; s < 16; s <<= 1) {
        f32x4 o;
        o[0] = __shfl_xor(rs[0], s); o[1] = __shfl_xor(rs[1], s);
        o[2] = __shfl_xor(rs[2], s); o[3] = __shfl_xor(rs[3], s);
        rs += o;
      }
      lrow[rt] = lrow[rt] * alpha + rs;
    }

    // PV: A = P (rows=q, k=key local), B = V^T (col=d, k=key local)
#pragma unroll
    for (int kc = 0; kc < 2; kc++) {
      bf16x8 pa0 = *(const bf16x8*)&s_p[w][lm][kc * 32 + l4 * 8];
      bf16x8 pa1 = *(const bf16x8*)&s_p[w][16 + lm][kc * 32 + l4 * 8];
#pragma unroll
      for (int dt = 0; dt < 8; dt++) {
        bf16x8 vb = *(const bf16x8*)&s_vt[dt * 16 + lm][kc * 32 + l4 * 8];
        O[0][dt] = mfma16(pa0, vb, O[0][dt]);
        O[1][dt] = mfma16(pa1, vb, O[1][dt]);
      }
    }
    __syncthreads();
  }

  // epilogue: normalize and scatter to original row order
#pragma unroll
  for (int rt = 0; rt < 2; rt++) {
    f32x4 inv;
#pragma unroll
    for (int r = 0; r < 4; r++) inv[r] = 1.0f / lrow[rt][r];
    int orow[4];
#pragma unroll
    for (int r = 0; r < 4; r++)
      orow[r] = q_idx[bh * Nseq + c * BLKSZ + w * 32 + rt * 16 + l4 * 4 + r];
#pragma unroll
    for (int r = 0; r < 4; r++) {
      float* op = out + ((size_t)bh * Nseq + orow[r]) * Dh + lm;
#pragma unroll
      for (int dt = 0; dt < 8; dt++) op[dt * 16] = O[rt][dt][r] * inv[r];
    }
  }
}

extern "C" void kernel_launch(void* const* d_in, const int* in_sizes, int n_in,
                              void* d_out, int out_size, void* d_ws, size_t ws_size,
                              hipStream_t stream) {
  const float* q    = (const float*)d_in[0];
  const float* k    = (const float*)d_in[1];
  const float* v    = (const float*)d_in[2];
  const float* proj = (const float*)d_in[3];
  const int* samp   = (const int*)d_in[4];
  float* out = (float*)d_out;

  int* buckets = (int*)d_ws;                   // [2][32][8192]
  int* idx = buckets + 2 * Hh * Nseq;          // [2][32][8192]: q_idx, k_idx

  lsh_hash_kernel<<<(2 * Hh * Nseq) / 256, 256, 0, stream>>>(q, k, proj, buckets);
  bucket_sort_kernel<<<2 * Hh, 64, 0, stream>>>(buckets, idx);
  hyper_attn_kernel<<<dim3(NBd, Hh), 512, 0, stream>>>(
      q, k, v, samp, idx /*q_idx*/, idx + Hh * Nseq /*k_idx*/, out);
}